// Round 5
// baseline (344.859 us; speedup 1.0000x reference)
//
#include <hip/hip_runtime.h>

#define BB 2048
#define NN 200
#define DD 128
#define HH 8

typedef float f4v __attribute__((ext_vector_type(4)));

// ---------------------------------------------------------------------------
// Kernel 1: v[b][d] = sum_h Wr[h] * tanh( bq[d*8+h] + dot(q[b,:], Wq[d*8+h,:]) )
// Grid (4 j-chunks x 128 b-chunks), 256 threads. Thread owns one j = d*8+h,
// register-blocks 16 b's. Wq staged transposed in LDS (lane-consecutive reads),
// q read via wave-uniform scalar loads.  ~537 MFLOP total -> a few us.
// (unchanged from verified baseline)
// ---------------------------------------------------------------------------
__global__ __launch_bounds__(256) void proj_kernel(
    const float* __restrict__ q,    // (B, 128)
    const float* __restrict__ Wq,   // (1024, 128)
    const float* __restrict__ bq,   // (1024)
    const float* __restrict__ Wr,   // (1, 8)
    float* __restrict__ v)          // (B, 128)
{
    __shared__ float wq_s[32][257];           // [k within tile][j within chunk], padded
    const int t  = threadIdx.x;               // 0..255
    const int jc = blockIdx.x;                // 0..3   -> j chunk of 256
    const int b0 = blockIdx.y * 16;           // 0..2047 in steps of 16
    const int j  = jc * 256 + t;

    float acc[16];
#pragma unroll
    for (int i = 0; i < 16; ++i) acc[i] = 0.f;

    for (int kt = 0; kt < 4; ++kt) {          // k tiles of 32
        __syncthreads();
#pragma unroll
        for (int i = 0; i < 8; ++i) {
            int idx = t + 256 * i;            // 0..2047 f4 slots
            int jj  = idx >> 3;               // 0..255
            int kf  = idx & 7;                // 0..7
            const float4 w4 = *(const float4*)(Wq + (size_t)(jc*256 + jj)*128 + kt*32 + kf*4);
            wq_s[kf*4+0][jj] = w4.x;
            wq_s[kf*4+1][jj] = w4.y;
            wq_s[kf*4+2][jj] = w4.z;
            wq_s[kf*4+3][jj] = w4.w;
        }
        __syncthreads();

        float wreg[32];
#pragma unroll
        for (int k = 0; k < 32; ++k) wreg[k] = wq_s[k][t];   // lane-consecutive: conflict-free

#pragma unroll
        for (int bb = 0; bb < 16; ++bb) {
            const float* qrow = q + (size_t)(b0 + bb)*128 + kt*32;  // wave-uniform -> s_load
            float s = 0.f;
#pragma unroll
            for (int k = 0; k < 32; ++k) s = fmaf(qrow[k], wreg[k], s);
            acc[bb] += s;
        }
    }

    const float bqj = bq[j];
    const float wrh = Wr[j & 7];
    const int   d   = j >> 3;
#pragma unroll
    for (int bb = 0; bb < 16; ++bb) {
        float p = tanhf(acc[bb] + bqj) * wrh;
        p += __shfl_xor(p, 1);
        p += __shfl_xor(p, 2);
        p += __shfl_xor(p, 4);
        if ((t & 7) == 0) v[(size_t)(b0 + bb)*128 + d] = p;
    }
}

// ---------------------------------------------------------------------------
// Kernel 2: one block per b; online softmax over N=200 in 3 chunks {64,64,72}.
// 512 threads = 16 half-waves; half-wave owns rows {half + 16*i}.
// EXACT round-2 structure (verified 320 us) with ONE change: item loads are
// PLAIN global loads, not __builtin_nontemporal_load.  Single-variable A/B:
// NT sets the no-allocate/bypass bits on global_load_dwordx4; if NT reads are
// serviced at reduced sector efficiency, the cacheable path recovers ~2x read
// BW on the 210 MB item stream.  Item has no reuse, so L2 pollution from
// cacheable reads is harmless.
//
// ZERO in-loop synchronization: each half-wave carries a PRIVATE flash state
// (m_h, l_h, o_h[4]) across all chunks, rescaled lane-locally; the 16 states
// merge ONCE at the end (identical math to reference's global-max softmax).
//
// LDS ~9.6 KB; ~45 live VGPRs -> fits the 64-VGPR cap of
// __launch_bounds__(512, 8): 4 blocks/CU, 32 waves/CU.
// ---------------------------------------------------------------------------
__global__ __launch_bounds__(512, 8) void attn_kernel(
    const float* __restrict__ item,  // (B, 200, 128)
    const int*   __restrict__ mask,  // (B, 200) as int32
    const float* __restrict__ v,     // (B, 128)
    float* __restrict__ out)         // (B, 128)
{
    __shared__ float  mask_s[NN];                   // 0.0 / 1.0
    __shared__ float2 ml_s[16];                     // final (m_h, l_h) per half
    __shared__ __align__(16) float stage[16][132];  // final o combine, padded

    const int t    = threadIdx.x;      // 0..511
    const int b    = blockIdx.x;
    const int seg  = t & 31;           // f4 segment within a row
    const int half = t >> 5;           // 0..15: half-wave id = row group

    const f4v vreg = *(const f4v*)(v + (size_t)b*128 + seg*4);
    const float* itemb = item + (size_t)b * (NN * 128);

    // stage mask as float once (coalesced; broadcast reads later)
    if (t < NN) mask_s[t] = mask[(size_t)b * NN + t] ? 1.f : 0.f;

    // ---- prefetch chunk 0 rows into registers (plain cacheable loads) ----
    f4v pre[5];
#pragma unroll
    for (int i = 0; i < 5; ++i) {
        const int row = half + 16*i;
        pre[i] = (f4v)0.f;
        if (row < 64)
            pre[i] = *(const f4v*)(itemb + (size_t)row*128 + seg*4);
    }
    __syncthreads();   // mask_s visible (the ONLY pre-epilogue barrier)

    float mh = -3e38f, lh = 0.f;
    f4v oh = (f4v)0.f;

    for (int c = 0; c < 3; ++c) {
        const int base = c * 64;
        const int rows = (c == 2) ? 72 : 64;

        // ---- dot against v; 32-lane butterfly => all lanes hold pp[i] ----
        float pp[5];
#pragma unroll
        for (int i = 0; i < 5; ++i) {
            const f4v f = pre[i];
            float s = f[0]*vreg[0] + f[1]*vreg[1] + f[2]*vreg[2] + f[3]*vreg[3];
#pragma unroll
            for (int off = 16; off >= 1; off >>= 1)
                s += __shfl_xor(s, off);
            pp[i] = s;
        }

        // ---- private running max over this half's valid rows (unmasked) ----
        float mn = mh;
#pragma unroll
        for (int i = 0; i < 5; ++i)
            if (half + 16*i < rows) mn = fmaxf(mn, pp[i]);

        const float alpha = __expf(mh - mn);   // chunk 0: exp(-3e38-x) -> 0
        mh = mn;
        lh *= alpha;
        oh[0] *= alpha; oh[1] *= alpha; oh[2] *= alpha; oh[3] *= alpha;

        // ---- masked exp weights + lane-local weighted accumulate ----
#pragma unroll
        for (int i = 0; i < 5; ++i) {
            const int row = half + 16*i;
            if (row < rows) {
                const float w = mask_s[base + row] * __expf(pp[i] - mn);
                lh += w;
                oh[0] = fmaf(w, pre[i][0], oh[0]);
                oh[1] = fmaf(w, pre[i][1], oh[1]);
                oh[2] = fmaf(w, pre[i][2], oh[2]);
                oh[3] = fmaf(w, pre[i][3], oh[3]);
            }
        }

        // ---- pre[] dead: issue next chunk's loads (in flight across the
        //      back-edge; no barrier anywhere in this loop) ----
        if (c < 2) {
            const int nbase = (c + 1) * 64;
            const int nrows = (c == 1) ? 72 : 64;
#pragma unroll
            for (int i = 0; i < 5; ++i) {
                const int row = half + 16*i;
                pre[i] = (f4v)0.f;
                if (row < nrows)
                    pre[i] = *(const f4v*)(itemb + (size_t)(nbase + row)*128 + seg*4);
            }
        }
    }

    // ---- merge the 16 private flash states, once ----
    if (seg == 0) ml_s[half] = make_float2(mh, lh);
    *(f4v*)(&stage[half][seg*4]) = oh;     // lane-consecutive f4: conflict-free
    __syncthreads();

    if (t < 128) {
        float mg = -3e38f;
#pragma unroll
        for (int h = 0; h < 16; ++h) mg = fmaxf(mg, ml_s[h].x);
        float lsum = 0.f, tot = 0.f;
#pragma unroll
        for (int h = 0; h < 16; ++h) {
            const float sc = __expf(ml_s[h].x - mg);
            lsum += ml_s[h].y * sc;
            tot  = fmaf(stage[h][t], sc, tot);   // consecutive lanes: conflict-free
        }
        const float denom = (lsum < 1e-7f) ? (lsum + 1.f) : lsum;
        out[(size_t)b * 128 + t] = tot / denom;
    }
}

// ---------------------------------------------------------------------------
extern "C" void kernel_launch(void* const* d_in, const int* in_sizes, int n_in,
                              void* d_out, int out_size, void* d_ws, size_t ws_size,
                              hipStream_t stream) {
    const float* item = (const float*)d_in[0];   // (2048, 200, 128)
    const float* q    = (const float*)d_in[1];   // (2048, 128)
    const int*   mask = (const int*)  d_in[2];   // (2048, 200, 1) bool -> int32
    const float* Wq   = (const float*)d_in[3];   // (1024, 128)
    const float* bq   = (const float*)d_in[4];   // (1024)
    const float* Wr   = (const float*)d_in[5];   // (1, 8)
    float* out = (float*)d_out;                  // (2048, 128)
    float* v   = (float*)d_ws;                   // scratch: 2048*128*4 = 1 MiB

    proj_kernel<<<dim3(4, 128), 256, 0, stream>>>(q, Wq, bq, Wr, v);
    attn_kernel<<<dim3(BB), 512, 0, stream>>>(item, mask, v, out);
}

// Round 7
// 329.372 us; speedup vs baseline: 1.0470x; 1.0470x over previous
//
#include <hip/hip_runtime.h>

#define BB 2048
#define NN 200
#define DD 128
#define HH 8

typedef float f4v __attribute__((ext_vector_type(4)));

// ---------------------------------------------------------------------------
// Kernel 1: v[b][d] = sum_h Wr[h] * tanh( bq[d*8+h] + dot(q[b,:], Wq[d*8+h,:]) )
// (unchanged from verified baseline)
// ---------------------------------------------------------------------------
__global__ __launch_bounds__(256) void proj_kernel(
    const float* __restrict__ q,    // (B, 128)
    const float* __restrict__ Wq,   // (1024, 128)
    const float* __restrict__ bq,   // (1024)
    const float* __restrict__ Wr,   // (1, 8)
    float* __restrict__ v)          // (B, 128)
{
    __shared__ float wq_s[32][257];           // [k within tile][j within chunk], padded
    const int t  = threadIdx.x;               // 0..255
    const int jc = blockIdx.x;                // 0..3   -> j chunk of 256
    const int b0 = blockIdx.y * 16;           // 0..2047 in steps of 16
    const int j  = jc * 256 + t;

    float acc[16];
#pragma unroll
    for (int i = 0; i < 16; ++i) acc[i] = 0.f;

    for (int kt = 0; kt < 4; ++kt) {          // k tiles of 32
        __syncthreads();
#pragma unroll
        for (int i = 0; i < 8; ++i) {
            int idx = t + 256 * i;            // 0..2047 f4 slots
            int jj  = idx >> 3;               // 0..255
            int kf  = idx & 7;                // 0..7
            const float4 w4 = *(const float4*)(Wq + (size_t)(jc*256 + jj)*128 + kt*32 + kf*4);
            wq_s[kf*4+0][jj] = w4.x;
            wq_s[kf*4+1][jj] = w4.y;
            wq_s[kf*4+2][jj] = w4.z;
            wq_s[kf*4+3][jj] = w4.w;
        }
        __syncthreads();

        float wreg[32];
#pragma unroll
        for (int k = 0; k < 32; ++k) wreg[k] = wq_s[k][t];   // lane-consecutive: conflict-free

#pragma unroll
        for (int bb = 0; bb < 16; ++bb) {
            const float* qrow = q + (size_t)(b0 + bb)*128 + kt*32;  // wave-uniform -> s_load
            float s = 0.f;
#pragma unroll
            for (int k = 0; k < 32; ++k) s = fmaf(qrow[k], wreg[k], s);
            acc[bb] += s;
        }
    }

    const float bqj = bq[j];
    const float wrh = Wr[j & 7];
    const int   d   = j >> 3;
#pragma unroll
    for (int bb = 0; bb < 16; ++bb) {
        float p = tanhf(acc[bb] + bqj) * wrh;
        p += __shfl_xor(p, 1);
        p += __shfl_xor(p, 2);
        p += __shfl_xor(p, 4);
        if ((t & 7) == 0) v[(size_t)(b0 + bb)*128 + d] = p;
    }
}

// ---------------------------------------------------------------------------
// Kernel 2: one block per b; online softmax over N=200 in 3 chunks {64,64,72}.
// 512 threads = 16 half-waves; half-wave owns rows {half + 16*i}.
//
// DEPTH-3 LOAD PIPELINE (the change vs the verified 320-us round-2 kernel):
// ALL chunk loads (pre0/pre1/pre2, <=13 f4 per thread) are issued UP FRONT,
// before the barrier.  Round-2's "prefetch at end of chunk c" had ~zero
// issue-to-use distance (the next instruction after the issue was chunk
// c+1's vmcnt-wait), so each wave serially paid a full loaded-HBM latency
// per chunk (3x/block) and SIMD util capped ~50% -- matching the observed
// ~half-of-achievable BW.  With all loads in flight, a wave pays ONE
// pipeline-fill latency per block; counted vmcnt waits (compiler-emitted
// for straight-line code) gate each chunk on only its own 4-5 loads.
//
// Register cost ~52 VGPR of load buffer -> ~85 total, so the (512,8) 64-VGPR
// cap is dropped: __launch_bounds__(512,3) -> 2-3 blocks/CU (16-24 waves).
// Even 16 waves/CU x 15 KB in flight >> the ~10 B/cyc/CU HBM fair share:
// the kernel becomes BW-bound instead of latency-bound.
//
// NT loads kept: A/B round 2 (NT, 320) vs round 5 (cacheable, 345) showed
// NT is worth ~25 us on this stream.
//
// Flash math unchanged from round 2 (verified): private per-half-wave
// (m_h, l_h, o_h[4]) state, merged once in the epilogue.
// ---------------------------------------------------------------------------
__global__ __launch_bounds__(512, 3) void attn_kernel(
    const float* __restrict__ item,  // (B, 200, 128)
    const int*   __restrict__ mask,  // (B, 200) as int32
    const float* __restrict__ v,     // (B, 128)
    float* __restrict__ out)         // (B, 128)
{
    __shared__ float  mask_s[NN];                   // 0.0 / 1.0
    __shared__ float2 ml_s[16];                     // final (m_h, l_h) per half
    __shared__ __align__(16) float stage[16][132];  // final o combine, padded

    const int t    = threadIdx.x;      // 0..511
    const int b    = blockIdx.x;
    const int seg  = t & 31;           // f4 segment within a row
    const int half = t >> 5;           // 0..15: half-wave id = row group

    const f4v vreg = *(const f4v*)(v + (size_t)b*128 + seg*4);
    const float* itemb = item + (size_t)b * (NN * 128);

    // stage mask as float once (coalesced; broadcast reads later)
    if (t < NN) mask_s[t] = mask[(size_t)b * NN + t] ? 1.f : 0.f;

    // ---- issue ALL three chunks' loads up front (depth-3 pipeline) ----
    f4v pre0[5], pre1[5], pre2[5];
#pragma unroll
    for (int i = 0; i < 5; ++i) {
        const int row = half + 16*i;
        pre0[i] = (f4v)0.f; pre1[i] = (f4v)0.f; pre2[i] = (f4v)0.f;
        if (row < 64) {
            pre0[i] = __builtin_nontemporal_load(
                (const f4v*)(itemb + (size_t)row*128        + seg*4));
            pre1[i] = __builtin_nontemporal_load(
                (const f4v*)(itemb + (size_t)(64 + row)*128 + seg*4));
        }
        if (row < 72)
            pre2[i] = __builtin_nontemporal_load(
                (const f4v*)(itemb + (size_t)(128 + row)*128 + seg*4));
    }
    __syncthreads();   // mask_s visible (the ONLY pre-epilogue barrier)

    float mh = -3e38f, lh = 0.f;
    f4v oh = (f4v)0.f;

    // ---- per-chunk body (static indexing; PRE consumed, then dead) ----
#define CHUNK_BODY(PRE, BASE, ROWS)                                          \
    {                                                                        \
        float pp[5];                                                         \
        _Pragma("unroll")                                                    \
        for (int i = 0; i < 5; ++i) {                                        \
            const f4v f = PRE[i];                                            \
            float s = f[0]*vreg[0] + f[1]*vreg[1] + f[2]*vreg[2] + f[3]*vreg[3]; \
            _Pragma("unroll")                                                \
            for (int off = 16; off >= 1; off >>= 1)                          \
                s += __shfl_xor(s, off);                                     \
            pp[i] = s;                                                       \
        }                                                                    \
        float mn = mh;                                                       \
        _Pragma("unroll")                                                    \
        for (int i = 0; i < 5; ++i)                                          \
            if (half + 16*i < (ROWS)) mn = fmaxf(mn, pp[i]);                 \
        const float alpha = __expf(mh - mn);                                 \
        mh = mn;                                                             \
        lh *= alpha;                                                         \
        oh[0] *= alpha; oh[1] *= alpha; oh[2] *= alpha; oh[3] *= alpha;      \
        _Pragma("unroll")                                                    \
        for (int i = 0; i < 5; ++i) {                                        \
            const int row = half + 16*i;                                     \
            if (row < (ROWS)) {                                              \
                const float w = mask_s[(BASE) + row] * __expf(pp[i] - mn);   \
                lh += w;                                                     \
                oh[0] = fmaf(w, PRE[i][0], oh[0]);                           \
                oh[1] = fmaf(w, PRE[i][1], oh[1]);                           \
                oh[2] = fmaf(w, PRE[i][2], oh[2]);                           \
                oh[3] = fmaf(w, PRE[i][3], oh[3]);                           \
            }                                                                \
        }                                                                    \
    }

    CHUNK_BODY(pre0,   0, 64)
    CHUNK_BODY(pre1,  64, 64)
    CHUNK_BODY(pre2, 128, 72)
#undef CHUNK_BODY

    // ---- merge the 16 private flash states, once ----
    if (seg == 0) ml_s[half] = make_float2(mh, lh);
    *(f4v*)(&stage[half][seg*4]) = oh;     // lane-consecutive f4: conflict-free
    __syncthreads();

    if (t < 128) {
        float mg = -3e38f;
#pragma unroll
        for (int h = 0; h < 16; ++h) mg = fmaxf(mg, ml_s[h].x);
        float lsum = 0.f, tot = 0.f;
#pragma unroll
        for (int h = 0; h < 16; ++h) {
            const float sc = __expf(ml_s[h].x - mg);
            lsum += ml_s[h].y * sc;
            tot  = fmaf(stage[h][t], sc, tot);   // consecutive lanes: conflict-free
        }
        const float denom = (lsum < 1e-7f) ? (lsum + 1.f) : lsum;
        out[(size_t)b * 128 + t] = tot / denom;
    }
}

// ---------------------------------------------------------------------------
extern "C" void kernel_launch(void* const* d_in, const int* in_sizes, int n_in,
                              void* d_out, int out_size, void* d_ws, size_t ws_size,
                              hipStream_t stream) {
    const float* item = (const float*)d_in[0];   // (2048, 200, 128)
    const float* q    = (const float*)d_in[1];   // (2048, 128)
    const int*   mask = (const int*)  d_in[2];   // (2048, 200, 1) bool -> int32
    const float* Wq   = (const float*)d_in[3];   // (1024, 128)
    const float* bq   = (const float*)d_in[4];   // (1024)
    const float* Wr   = (const float*)d_in[5];   // (1, 8)
    float* out = (float*)d_out;                  // (2048, 128)
    float* v   = (float*)d_ws;                   // scratch: 2048*128*4 = 1 MiB

    proj_kernel<<<dim3(4, 128), 256, 0, stream>>>(q, Wq, bq, Wr, v);
    attn_kernel<<<dim3(BB), 512, 0, stream>>>(item, mask, v, out);
}